// Round 2
// baseline (782.946 us; speedup 1.0000x reference)
//
#include <hip/hip_runtime.h>
#include <math.h>

typedef __attribute__((ext_vector_type(8))) __bf16 bf16x8;
typedef __attribute__((ext_vector_type(4))) float f32x4;

#define NB 8
#define NC 2048
#define NHW 784
#define NROWS 6272   /* NB*NHW */
#define NM 8192
#define NNEI 9
#define NCAND 16

static_assert(NROWS == NB * NHW, "dims");

// ---------- prep features: transpose [B,C,H,W] -> [N,C] fp32 + bf16 hi ----------
__global__ __launch_bounds__(256) void prep_f_kernel(const float* __restrict__ feat,
                                                     float* __restrict__ Af32,
                                                     __bf16* __restrict__ Ahi) {
  __shared__ float tile[32][33];
  int b = blockIdx.z;
  int c0 = blockIdx.y * 32;
  int hw0 = blockIdx.x * 32;
  int tx = threadIdx.x & 31, ty = threadIdx.x >> 5;
#pragma unroll
  for (int i = 0; i < 4; ++i) {
    int c = c0 + ty + i * 8;
    int hw = hw0 + tx;
    float v = 0.f;
    if (hw < NHW) v = feat[((size_t)b * NC + c) * NHW + hw];
    tile[ty + i * 8][tx] = v;   // tile[c_local][hw_local]
  }
  __syncthreads();
#pragma unroll
  for (int i = 0; i < 4; ++i) {
    int hwl = ty + i * 8;
    int hw = hw0 + hwl;
    if (hw < NHW) {
      int n = b * NHW + hw;
      float v = tile[tx][hwl];
      Af32[(size_t)n * NC + c0 + tx] = v;
      Ahi[(size_t)n * NC + c0 + tx] = (__bf16)v;
    }
  }
}

// ---------- prep memory bank: bf16 hi + row norms (fp32, selection-only) ----------
__global__ __launch_bounds__(256) void prep_mb_kernel(const float* __restrict__ mb,
                                                      __bf16* __restrict__ Bhi,
                                                      float* __restrict__ m2) {
  __shared__ float red[4];
  int m = blockIdx.x, tid = threadIdx.x;
  float ss = 0.f;
#pragma unroll
  for (int i = 0; i < NC / 256; ++i) {
    int c = tid + i * 256;
    float v = mb[(size_t)m * NC + c];
    Bhi[(size_t)m * NC + c] = (__bf16)v;
    ss += v * v;
  }
#pragma unroll
  for (int off = 32; off; off >>= 1) ss += __shfl_xor(ss, off);
  if ((tid & 63) == 0) red[tid >> 6] = ss;
  __syncthreads();
  if (tid == 0) m2[m] = red[0] + red[1] + red[2] + red[3];
}

// ---------- approx GEMM: dot[n][m] = fhi_n . mhi_m  (pure bf16, K=2048) ----------
// 128x128 tile, 4 waves (2x2 of 64x64), BK=64, XOR-swizzled LDS,
// global_load_lds width=16 with pre-swizzled global source.
__global__ __launch_bounds__(256) void gemm_kernel(const __bf16* __restrict__ Ahi,
                                                   const __bf16* __restrict__ Bhi,
                                                   float* __restrict__ dotbuf,
                                                   int rt0) {
  __shared__ __align__(16) char lds[32768];
  char* Ash = lds;
  char* Bsh = lds + 16384;
  int tid = threadIdx.x;
  int lane = tid & 63, w = tid >> 6;
  int rtl = blockIdx.x, mt = blockIdx.y;
  size_t n0 = (size_t)(rt0 + rtl) * 128;
  size_t m0 = (size_t)mt * 128;
  int wr = w >> 1, wc = w & 1;
  int l8 = lane & 7, ld8 = lane >> 3;
  int srcslot = l8 ^ ld8;

  f32x4 acc[4][4] = {};

  for (int kt = 0; kt < 32; ++kt) {
    int kk = kt << 6;
#pragma unroll
    for (int i = 0; i < 4; ++i) {
      int row = i * 32 + w * 8 + ld8;
      const char* srcA = (const char*)(Ahi + (n0 + row) * NC + kk) + srcslot * 16;
      const char* srcB = (const char*)(Bhi + (m0 + row) * NC + kk) + srcslot * 16;
      __builtin_amdgcn_global_load_lds((const __attribute__((address_space(1))) void*)srcA,
                                       (__attribute__((address_space(3))) void*)(Ash + i * 4096 + w * 1024),
                                       16, 0, 0);
      __builtin_amdgcn_global_load_lds((const __attribute__((address_space(1))) void*)srcB,
                                       (__attribute__((address_space(3))) void*)(Bsh + i * 4096 + w * 1024),
                                       16, 0, 0);
    }
    __syncthreads();
    int r = lane & 15, kq = lane >> 4;
    bf16x8 av[4][2], bv[4][2];
#pragma unroll
    for (int m = 0; m < 4; ++m)
#pragma unroll
      for (int ks = 0; ks < 2; ++ks) {
        int rowa = wr * 64 + m * 16 + r;
        av[m][ks] = *(const bf16x8*)(Ash + rowa * 128 + (((kq + ks * 4) ^ (rowa & 7)) << 4));
        int rowb = wc * 64 + m * 16 + r;
        bv[m][ks] = *(const bf16x8*)(Bsh + rowb * 128 + (((kq + ks * 4) ^ (rowb & 7)) << 4));
      }
#pragma unroll
    for (int m = 0; m < 4; ++m)
#pragma unroll
      for (int nn2 = 0; nn2 < 4; ++nn2)
#pragma unroll
        for (int ks = 0; ks < 2; ++ks)
          acc[m][nn2] = __builtin_amdgcn_mfma_f32_16x16x32_bf16(av[m][ks], bv[nn2][ks], acc[m][nn2], 0, 0, 0);
    __syncthreads();
  }

  int r4 = (lane >> 4) * 4, cL = lane & 15;  // C/D: col=lane&15, row=(lane>>4)*4+reg (m89)
#pragma unroll
  for (int m = 0; m < 4; ++m)
#pragma unroll
    for (int nn2 = 0; nn2 < 4; ++nn2)
#pragma unroll
      for (int q = 0; q < 4; ++q) {
        size_t row = (size_t)rtl * 128 + wr * 64 + m * 16 + r4 + q;
        size_t col = m0 + wc * 64 + nn2 * 16 + cL;
        dotbuf[row * NM + col] = acc[m][nn2][q];
      }
}

// ---------- per-row top-16 candidates by approx score = m2 - 2*dot ----------
__global__ __launch_bounds__(256) void sel16_kernel(const float* __restrict__ dotbuf,
                                                    const float* __restrict__ m2,
                                                    int* __restrict__ cand,
                                                    int row0) {
  __shared__ float scL[NM];
  __shared__ float swv[4];
  __shared__ int swi[4];
  int rl = blockIdx.x;
  int n = row0 + rl;
  int tid = threadIdx.x;

  const float* drow = dotbuf + (size_t)rl * NM;
#pragma unroll
  for (int i = 0; i < NM / 256; ++i) {
    int m = tid + i * 256;
    scL[i * 256 + tid] = m2[m] - 2.f * drow[m];
  }
  __syncthreads();

  for (int r = 0; r < NCAND; ++r) {
    float bv = 3.4e38f;
    int bi = 0x7fffffff;
#pragma unroll
    for (int i = 0; i < NM / 256; ++i) {
      float v = scL[i * 256 + tid];
      if (v < bv) { bv = v; bi = (i << 8) + tid; }
    }
#pragma unroll
    for (int off = 32; off; off >>= 1) {
      float ov = __shfl_xor(bv, off);
      int oi = __shfl_xor(bi, off);
      if (ov < bv || (ov == bv && oi < bi)) { bv = ov; bi = oi; }
    }
    if ((tid & 63) == 0) { swv[tid >> 6] = bv; swi[tid >> 6] = bi; }
    __syncthreads();
    if (tid == 0) {
      float Bv = swv[0]; int Bi = swi[0];
#pragma unroll
      for (int qq = 1; qq < 4; ++qq)
        if (swv[qq] < Bv || (swv[qq] == Bv && swi[qq] < Bi)) { Bv = swv[qq]; Bi = swi[qq]; }
      cand[(size_t)n * NCAND + r] = Bi;
      scL[(Bi >> 8) * 256 + (Bi & 255)] = 3.4e38f;   // knock out winner
    }
    __syncthreads();
  }
}

// ---------- exact fp64 rescore of 16 candidates -> top-9 + row-mean distance ----------
__global__ __launch_bounds__(256) void rescore_kernel(const float* __restrict__ Af32,
                                                      const float* __restrict__ mb,
                                                      const int* __restrict__ cand,
                                                      int* __restrict__ tki,
                                                      float* __restrict__ dsv) {
  __shared__ float fbuf[NC];
  __shared__ double dred[4];
  __shared__ double d2s[NCAND];
  __shared__ int cidx[NCAND];
  int n = blockIdx.x, tid = threadIdx.x;
#pragma unroll
  for (int i = 0; i < NC / 256; ++i)
    fbuf[tid + i * 256] = Af32[(size_t)n * NC + tid + i * 256];
  if (tid < NCAND) cidx[tid] = cand[(size_t)n * NCAND + tid];
  __syncthreads();

  for (int j = 0; j < NCAND; ++j) {
    const float* mrow = mb + (size_t)cidx[j] * NC;
    double acc = 0.0;
#pragma unroll
    for (int i = 0; i < NC / 256; ++i) {
      int c = tid + i * 256;
      double d = (double)fbuf[c] - (double)mrow[c];
      acc += d * d;
    }
#pragma unroll
    for (int off = 32; off; off >>= 1) acc += __shfl_xor(acc, off);
    if ((tid & 63) == 0) dred[tid >> 6] = acc;
    __syncthreads();
    if (tid == 0) d2s[j] = dred[0] + dred[1] + dred[2] + dred[3];
    __syncthreads();
  }

  if (tid == 0) {
    double dacc = 0.0;
    bool used[NCAND] = {};
    for (int r = 0; r < NNEI; ++r) {
      int bj = 0; double bv = 1e300; int bidx = 0x7fffffff;
      for (int j = 0; j < NCAND; ++j) {
        if (used[j]) continue;
        if (d2s[j] < bv || (d2s[j] == bv && cidx[j] < bidx)) { bv = d2s[j]; bidx = cidx[j]; bj = j; }
      }
      used[bj] = true;
      tki[(size_t)n * NNEI + r] = bidx;
      dacc += sqrt(bv > 0.0 ? bv : 0.0);
    }
    dsv[n] = (float)(dacc * (1.0 / 9.0));
  }
}

// ---------- global stats of row-mean distance (broadcast [N,C] semantics, ddof=1) ----------
__global__ __launch_bounds__(256) void stats_kernel(const float* __restrict__ dsv,
                                                    float* __restrict__ stats) {
  __shared__ float buf[NROWS];
  __shared__ float red[4];
  int tid = threadIdx.x;
  float s = 0.f;
  for (int i = tid; i < NROWS; i += 256) { float v = dsv[i]; buf[i] = v; s += v; }
#pragma unroll
  for (int off = 32; off; off >>= 1) s += __shfl_xor(s, off);
  if ((tid & 63) == 0) red[tid >> 6] = s;
  __syncthreads();
  float mu = (red[0] + red[1] + red[2] + red[3]) * (1.f / NROWS);
  __syncthreads();
  float q = 0.f;
  for (int i = tid; i < NROWS; i += 256) { float d = buf[i] - mu; q += d * d; }
#pragma unroll
  for (int off = 32; off; off >>= 1) q += __shfl_xor(q, off);
  if ((tid & 63) == 0) red[tid >> 6] = q;
  __syncthreads();
  if (tid == 0) {
    float SSb = (red[0] + red[1] + red[2] + red[3]) * (float)NC;  // broadcast to [N,C]
    float var = SSb / ((float)NROWS * (float)NC - 1.f);
    stats[0] = mu;
    stats[1] = 1.f / (sqrtf(var) + 1e-8f);
  }
}

// ---------- fused: gather 9 neighbors, influence norm, sigmoid noise, maps ----------
__global__ __launch_bounds__(256) void fuse_kernel(const float* __restrict__ Af32,
                                                   const float* __restrict__ mb,
                                                   const float* __restrict__ noise,
                                                   const float* __restrict__ iw,
                                                   const float* __restrict__ dwp,
                                                   const int* __restrict__ topk_idx,
                                                   const float* __restrict__ dsv,
                                                   const float* __restrict__ stats,
                                                   float* __restrict__ noised_tmp,
                                                   float* __restrict__ out_infl,
                                                   float* __restrict__ out_nstd) {
  __shared__ int idx[NNEI];
  __shared__ float red[4];
  int n = blockIdx.x;
  int tid = threadIdx.x;
  if (tid < NNEI) idx[tid] = topk_idx[(size_t)n * NNEI + tid];
  __syncthreads();

  float s_c[8], f_c[8];
  float sum_s = 0.f, sum_s2 = 0.f;
#pragma unroll
  for (int i = 0; i < 8; ++i) {
    int c = tid + i * 256;
    float f = Af32[(size_t)n * NC + c];
    f_c[i] = f;
    float a = 0.f;
#pragma unroll
    for (int j = 0; j < NNEI; ++j)
      a += fabsf(f - mb[(size_t)idx[j] * NC + c]);
    float s = (a * (1.f / 9.f)) * iw[c];
    s_c[i] = s;
    sum_s += s;
    sum_s2 += s * s;
  }
#pragma unroll
  for (int off = 32; off; off >>= 1) sum_s += __shfl_xor(sum_s, off);
  if ((tid & 63) == 0) red[tid >> 6] = sum_s;
  __syncthreads();
  float tot_s = red[0] + red[1] + red[2] + red[3];
  __syncthreads();
#pragma unroll
  for (int off = 32; off; off >>= 1) sum_s2 += __shfl_xor(sum_s2, off);
  if ((tid & 63) == 0) red[tid >> 6] = sum_s2;
  __syncthreads();
  float tot_s2 = red[0] + red[1] + red[2] + red[3];
  __syncthreads();

  float mu = tot_s * (1.f / NC);
  float var = (tot_s2 - (float)NC * mu * mu) * (1.f / (NC - 1));
  float rstd = 1.f / (sqrtf(fmaxf(var, 0.f)) + 1e-8f);
  float dnorm = (dsv[n] - stats[0]) * stats[1];
  float dwv = dwp[0];

  float nsum = 0.f;
#pragma unroll
  for (int i = 0; i < 8; ++i) {
    int c = tid + i * 256;
    float inorm = (s_c[i] - mu) * rstd;
    float comb = inorm + dwv * dnorm;
    float sig = 1.f / (1.f + expf(-comb));
    float nstd = 0.01f + 0.49f * sig;
    nsum += nstd;
    noised_tmp[(size_t)n * NC + c] = f_c[i] + noise[(size_t)n * NC + c] * nstd;
  }
#pragma unroll
  for (int off = 32; off; off >>= 1) nsum += __shfl_xor(nsum, off);
  if ((tid & 63) == 0) red[tid >> 6] = nsum;
  __syncthreads();
  if (tid == 0) {
    out_infl[n] = tot_s * (1.f / NC);
    out_nstd[n] = (red[0] + red[1] + red[2] + red[3]) * (1.f / NC);
  }
}

// ---------- transpose noised [N,C] -> [B,C,H,W] ----------
__global__ __launch_bounds__(256) void transpose_kernel(const float* __restrict__ src,
                                                        float* __restrict__ dst) {
  __shared__ float tile[32][33];
  int b = blockIdx.z;
  int c0 = blockIdx.y * 32;
  int hw0 = blockIdx.x * 32;
  int tx = threadIdx.x & 31, ty = threadIdx.x >> 5;
#pragma unroll
  for (int i = 0; i < 4; ++i) {
    int hw = hw0 + ty + i * 8;
    if (hw < NHW) tile[ty + i * 8][tx] = src[((size_t)(b * NHW + hw)) * NC + c0 + tx];
  }
  __syncthreads();
#pragma unroll
  for (int i = 0; i < 4; ++i) {
    int c = c0 + ty + i * 8;
    int hw = hw0 + tx;
    if (hw < NHW) dst[((size_t)b * NC + c) * NHW + hw] = tile[tx][ty + i * 8];
  }
}

extern "C" void kernel_launch(void* const* d_in, const int* in_sizes, int n_in,
                              void* d_out, int out_size, void* d_ws, size_t ws_size,
                              hipStream_t stream) {
  (void)in_sizes; (void)n_in; (void)out_size;
  const float* feat  = (const float*)d_in[0];
  const float* mb    = (const float*)d_in[1];
  const float* iw    = (const float*)d_in[2];
  const float* dwp   = (const float*)d_in[3];
  const float* noise = (const float*)d_in[4];
  float* out = (float*)d_out;
  float* out_noised = out;
  float* out_infl = out + (size_t)NB * NC * NHW;
  float* out_nstd = out_infl + NROWS;

  char* ws = (char*)d_ws;
  size_t off = 0;
  auto alloc = [&](size_t sz) -> char* {
    char* p = ws + off;
    off += (sz + 255) & ~(size_t)255;
    return p;
  };
  float* Af32 = (float*)alloc((size_t)NROWS * NC * 4);
  __bf16* Ahi = (__bf16*)alloc((size_t)NROWS * NC * 2);
  // shared region: Bhi (33.6 MB) during selection, noised_tmp (51.4 MB) after
  char* region = alloc((size_t)NROWS * NC * 4);
  __bf16* Bhi = (__bf16*)region;
  float* noised_tmp = (float*)region;
  float* m2v = (float*)alloc((size_t)NM * 4);
  int* candb = (int*)alloc((size_t)NROWS * NCAND * 4);
  int* tki = (int*)alloc((size_t)NROWS * NNEI * 4);
  float* dsv = (float*)alloc((size_t)NROWS * 4);
  float* stv = (float*)alloc(256);
  float* dotbuf = (float*)(ws + off);
  size_t avail = (ws_size > off) ? (ws_size - off) : 0;
  long CT = (long)(avail / ((size_t)128 * NM * 4));   // row-tiles per dot chunk
  if (CT < 1) CT = 1;
  if (CT > 49) CT = 49;

  prep_f_kernel<<<dim3(25, 64, NB), 256, 0, stream>>>(feat, Af32, Ahi);
  prep_mb_kernel<<<NM, 256, 0, stream>>>(mb, Bhi, m2v);
  for (int rt0 = 0; rt0 < 49; rt0 += (int)CT) {
    int ct = 49 - rt0;
    if (ct > CT) ct = (int)CT;
    gemm_kernel<<<dim3(ct, 64), 256, 0, stream>>>(Ahi, Bhi, dotbuf, rt0);
    sel16_kernel<<<ct * 128, 256, 0, stream>>>(dotbuf, m2v, candb, rt0 * 128);
  }
  rescore_kernel<<<NROWS, 256, 0, stream>>>(Af32, mb, candb, tki, dsv);
  stats_kernel<<<1, 256, 0, stream>>>(dsv, stv);
  fuse_kernel<<<NROWS, 256, 0, stream>>>(Af32, mb, noise, iw, dwp, tki, dsv, stv,
                                         noised_tmp, out_infl, out_nstd);
  transpose_kernel<<<dim3(25, 64, NB), 256, 0, stream>>>(noised_tmp, out_noised);
}